// Round 9
// baseline (253.848 us; speedup 1.0000x reference)
//
#include <hip/hip_runtime.h>
#include <math.h>

#define T_LEN 100
#define K_LEN 25
#define DLAT 64
#define DHID 128
#define CST 68    // h2s/aggs row stride (floats)
#define AST2 36   // packed adjacency row stride (u32)
#define TST 132   // reduction tile stride (floats)

// smem carve (float offsets).
// Live set A (phases 1-4): h2s(4352) + Asu(2304) + aggs(4352) = 11008
// Live set B (post-part4): tile(8448) + Pred(1024) + SQl/QQl/red(288) = 9760
// SMEM_F = max = 11008 floats = 44032 B.  (r7 bug: was sized to set B only,
// so aggs rows >=45 fell off the end of the LDS block -> garbage reads.)
#define OFF_H2S   0      // 4352 f  (64 x 68)
#define OFF_ASU   4352   // 2304 u32 (64 x 36 packed counts)
#define OFF_AGG   6656   // 4352 f  (64 x 68) ends at 11008
#define OFF_TILE  0      // 8448 f  (64 x 132)  [post-part4 only]
#define OFF_PRED  8448   // 1024 f  (S partials [4][128], Q partials [4][128])
#define OFF_SQL   9472   // 128 f
#define OFF_QQL   9600   // 128 f
#define OFF_RED   9728   // 32 f
#define SMEM_F    11008  // 44.03 KB -> 3 blocks/CU by LDS, >=2 by VGPR cap

__device__ __forceinline__ float dot4(float4 a, float4 b) {
    return a.x * b.x + a.y * b.y + a.z * b.z + a.w * b.w;
}

// Full-grid barrier. SAFE: grid = G <= 512; 44KB LDS and VGPR<=128
// (launch_bounds(512,4)) -> >=2 blocks/CU x 256 CUs = 512 all resident
// before any block waits (r4-proven fence/atomic pattern; r7 run confirmed
// the barriers complete on this grid).
__device__ __forceinline__ void gbar(unsigned* cnt, unsigned* flag,
                                     unsigned nb) {
    __syncthreads();
    if (threadIdx.x == 0) {
        __threadfence();
        unsigned t = __hip_atomic_fetch_add(cnt, 1u, __ATOMIC_ACQ_REL,
                                            __HIP_MEMORY_SCOPE_AGENT);
        if (t == nb - 1u) {
            __hip_atomic_store(flag, 1u, __ATOMIC_RELEASE,
                               __HIP_MEMORY_SCOPE_AGENT);
        } else {
            while (__hip_atomic_load(flag, __ATOMIC_ACQUIRE,
                                     __HIP_MEMORY_SCOPE_AGENT) == 0u)
                __builtin_amdgcn_s_sleep(8);
        }
        __threadfence();
    }
    __syncthreads();
}

// ---------------------------------------------------------------------------
// packU: Wm[c*100+i] (collapsed conv+fc1), Wm[6400+c]=b2,
//        upkQ[q][j][32]: q=0/1 rel_w lo/hi 32 ch, q=2/3 root_w lo/hi.
//        (512B-contiguous per (wave,q) -> mergeable s_load runs)
//        bar[0..7]=0 (grid-barrier state, rezeroed every iteration)
// ---------------------------------------------------------------------------
__global__ __launch_bounds__(256) void packU(const float* __restrict__ conv_w,
                                             const float* __restrict__ conv_b,
                                             const float* __restrict__ fc1_w,
                                             const float* __restrict__ fc1_b,
                                             const float* __restrict__ rel_w,
                                             const float* __restrict__ root_w,
                                             float* __restrict__ Wm,
                                             float* __restrict__ upkQ,
                                             unsigned* __restrict__ bar) {
    int idx = blockIdx.x * 256 + threadIdx.x;
    if (idx < 16384) {
        int q = idx >> 12, rem = idx & 4095;
        int j = rem >> 5, k = rem & 31;
        upkQ[idx] = (q < 2 ? rel_w : root_w)[j * DLAT + (q & 1) * 32 + k];
    } else if (idx < 16384 + 6400) {
        int t2 = idx - 16384;
        int c = t2 / T_LEN, i = t2 % T_LEN;
        int t0 = i - 12 > 0 ? i - 12 : 0;
        int t1 = i + 12 < T_LEN - 1 ? i + 12 : T_LEN - 1;
        float acc = 0.f;
        for (int t = t0; t <= t1; ++t)
            acc += fc1_w[t] * conv_w[c * K_LEN + (i - t + 12)];
        Wm[t2] = acc;
    } else if (idx < 16384 + 6400 + 64) {
        int c = idx - (16384 + 6400);
        float S = 0.f;
        for (int t = 0; t < T_LEN; ++t) S += fc1_w[t];
        Wm[6400 + c] = conv_b[c] * S + fc1_b[0];
    } else if (idx < 16384 + 6400 + 64 + 8) {
        bar[idx - (16384 + 6400 + 64)] = 0u;
    }
}

// ---------------------------------------------------------------------------
// fused: one block per graph, 512 thr = 8 waves, 44KB LDS.
// Pipe discipline (r6 lesson: LDS pipe was saturated by broadcast reads):
//   - per-lane data -> vector ds_read_b128 / coalesced VMEM
//   - wave-uniform data -> scalar s_load (contiguous runs only)
//   - reductions -> LDS transpose tile (no shfl/bpermute storms)
// ---------------------------------------------------------------------------
__global__ __launch_bounds__(512, 4) void fused(const float* __restrict__ x,
                                                const int* __restrict__ ei,
                                                const float* __restrict__ Wm,
                                                const float* __restrict__ upkQ,
                                                const float* __restrict__ rel_b,
                                                const float* __restrict__ gamma,
                                                const float* __restrict__ beta,
                                                const float* __restrict__ fc2_w,
                                                const float* __restrict__ fc2_b,
                                                float* __restrict__ Sg,
                                                float* __restrict__ Qg,
                                                float* __restrict__ abG,
                                                float* __restrict__ y,
                                                unsigned* __restrict__ bar,
                                                int E, int G, int N, int coop) {
    __shared__ float smem[SMEM_F];
    float* h2s = smem + OFF_H2S;
    unsigned* Asu = (unsigned*)(smem + OFF_ASU);
    float* aggs = smem + OFF_AGG;
    float* tile = smem + OFF_TILE;
    float* Pred = smem + OFF_PRED;
    float* SQl = smem + OFF_SQL;
    float* QQl = smem + OFF_QQL;
    float* red = smem + OFF_RED;

    const int tid = threadIdx.x;
    const int lane = tid & 63;
    const int w2 = __builtin_amdgcn_readfirstlane(tid >> 6);  // 0..7 uniform

    // bijective XCD swizzle (m204)
    const int nb = gridDim.x;
    int qq_ = nb >> 3, rr = nb & 7;
    int xc = blockIdx.x & 7, oo = blockIdx.x >> 3;
    const int g = (xc < rr ? xc * (qq_ + 1) : rr * (qq_ + 1) + (xc - rr) * qq_) + oo;

    const int epg = (G > 0) ? E / G : 0;
    const bool fast = (epg == 2048) && (E == G * 2048);

    // ---- 0. issue strided edge loads EARLY (drain after encoder) ----
    int es0 = 0, es1 = 0, es2 = 0, es3 = 0;
    int ed0 = 0, ed1 = 0, ed2 = 0, ed3 = 0;
    if (fast) {
        int e0 = g + tid * G;
        int st = 512 * G;
        es0 = ei[e0];           ed0 = ei[E + e0];
        es1 = ei[e0 + st];      ed1 = ei[E + e0 + st];
        es2 = ei[e0 + 2 * st];  ed2 = ei[E + e0 + 2 * st];
        es3 = ei[e0 + 3 * st];  ed3 = ei[E + e0 + 3 * st];
    }

    // zero packed adjacency (disjoint from encoder targets; no barrier needed)
    for (int i = tid; i < 64 * AST2; i += 512) Asu[i] = 0u;

    // ---- 1. encoder: lane = node; wave w2 -> channels [8w2, 8w2+8).
    //      x per-lane coalesced VMEM; W on the scalar path (r0-proven). ----
    {
        const float4* __restrict__ xp =
            (const float4*)(x + (size_t)(g * 64 + lane) * T_LEN);
        const float* Wb = Wm + w2 * 8 * T_LEN;  // wave-uniform -> s_load
        float acc[8];
#pragma unroll
        for (int c = 0; c < 8; ++c) acc[c] = 0.f;
        for (int tq = 0; tq < T_LEN / 4; ++tq) {
            float4 xv = xp[tq];
#pragma unroll
            for (int c = 0; c < 8; ++c) {
                const float* wr = Wb + c * T_LEN + tq * 4;
                acc[c] += xv.x * wr[0] + xv.y * wr[1] + xv.z * wr[2] + xv.w * wr[3];
            }
        }
        float4 o0, o1;
        o0.x = acc[0] + Wm[6400 + w2 * 8 + 0];
        o0.y = acc[1] + Wm[6400 + w2 * 8 + 1];
        o0.z = acc[2] + Wm[6400 + w2 * 8 + 2];
        o0.w = acc[3] + Wm[6400 + w2 * 8 + 3];
        o1.x = acc[4] + Wm[6400 + w2 * 8 + 4];
        o1.y = acc[5] + Wm[6400 + w2 * 8 + 5];
        o1.z = acc[6] + Wm[6400 + w2 * 8 + 6];
        o1.w = acc[7] + Wm[6400 + w2 * 8 + 7];
        *(float4*)&h2s[lane * CST + w2 * 8] = o0;
        *(float4*)&h2s[lane * CST + w2 * 8 + 4] = o1;
    }
    __syncthreads();  // S1: adj zeroed, h2s ready

    // ---- 2. LDS-atomic edge count (2 u16 counts per u32) ----
    if (fast) {
        atomicAdd(&Asu[(ed0 & 63) * AST2 + ((es0 & 63) >> 1)], 1u << ((es0 & 1) << 4));
        atomicAdd(&Asu[(ed1 & 63) * AST2 + ((es1 & 63) >> 1)], 1u << ((es1 & 1) << 4));
        atomicAdd(&Asu[(ed2 & 63) * AST2 + ((es2 & 63) >> 1)], 1u << ((es2 & 1) << 4));
        atomicAdd(&Asu[(ed3 & 63) * AST2 + ((es3 & 63) >> 1)], 1u << ((es3 & 1) << 4));
    } else {
        for (int e = g + tid * G; e < E; e += 512 * G) {
            int s = ei[e] & 63, d = ei[E + e] & 63;
            atomicAdd(&Asu[d * AST2 + (s >> 1)], 1u << ((s & 1) << 4));
        }
    }
    __syncthreads();  // S2

    // ---- 3. agg = A @ h2; thread owns n1 and n1+32 x 4 channels ----
    {
        int c4 = (tid & 15) * 4;
        int n1 = (tid >> 4);        // 0..31
        int n2 = n1 + 32;
        float4 a1 = {0.f, 0.f, 0.f, 0.f};
        float4 a2 = {0.f, 0.f, 0.f, 0.f};
        for (int s8 = 0; s8 < 8; ++s8) {
            uint4 u1 = *(const uint4*)&Asu[n1 * AST2 + s8 * 4];
            uint4 u2 = *(const uint4*)&Asu[n2 * AST2 + s8 * 4];
            const float* hb = &h2s[(8 * s8) * CST + c4];
            float4 h0 = *(const float4*)(hb + 0 * CST);
            float4 h1 = *(const float4*)(hb + 1 * CST);
            float4 h2v = *(const float4*)(hb + 2 * CST);
            float4 h3 = *(const float4*)(hb + 3 * CST);
            float4 h4 = *(const float4*)(hb + 4 * CST);
            float4 h5 = *(const float4*)(hb + 5 * CST);
            float4 h6 = *(const float4*)(hb + 6 * CST);
            float4 h7 = *(const float4*)(hb + 7 * CST);
            float c0 = (float)(u1.x & 0xffffu), c1 = (float)(u1.x >> 16);
            float c2 = (float)(u1.y & 0xffffu), c3 = (float)(u1.y >> 16);
            float c4a = (float)(u1.z & 0xffffu), c5 = (float)(u1.z >> 16);
            float c6 = (float)(u1.w & 0xffffu), c7 = (float)(u1.w >> 16);
            a1.x += c0 * h0.x + c1 * h1.x + c2 * h2v.x + c3 * h3.x +
                    c4a * h4.x + c5 * h5.x + c6 * h6.x + c7 * h7.x;
            a1.y += c0 * h0.y + c1 * h1.y + c2 * h2v.y + c3 * h3.y +
                    c4a * h4.y + c5 * h5.y + c6 * h6.y + c7 * h7.y;
            a1.z += c0 * h0.z + c1 * h1.z + c2 * h2v.z + c3 * h3.z +
                    c4a * h4.z + c5 * h5.z + c6 * h6.z + c7 * h7.z;
            a1.w += c0 * h0.w + c1 * h1.w + c2 * h2v.w + c3 * h3.w +
                    c4a * h4.w + c5 * h5.w + c6 * h6.w + c7 * h7.w;
            float d0 = (float)(u2.x & 0xffffu), d1 = (float)(u2.x >> 16);
            float d2 = (float)(u2.y & 0xffffu), d3 = (float)(u2.y >> 16);
            float d4 = (float)(u2.z & 0xffffu), d5 = (float)(u2.z >> 16);
            float d6 = (float)(u2.w & 0xffffu), d7 = (float)(u2.w >> 16);
            a2.x += d0 * h0.x + d1 * h1.x + d2 * h2v.x + d3 * h3.x +
                    d4 * h4.x + d5 * h5.x + d6 * h6.x + d7 * h7.x;
            a2.y += d0 * h0.y + d1 * h1.y + d2 * h2v.y + d3 * h3.y +
                    d4 * h4.y + d5 * h5.y + d6 * h6.y + d7 * h7.y;
            a2.z += d0 * h0.z + d1 * h1.z + d2 * h2v.z + d3 * h3.z +
                    d4 * h4.z + d5 * h5.z + d6 * h6.z + d7 * h7.z;
            a2.w += d0 * h0.w + d1 * h1.w + d2 * h2v.w + d3 * h3.w +
                    d4 * h4.w + d5 * h5.w + d6 * h6.w + d7 * h7.w;
        }
        *(float4*)&aggs[n1 * CST + c4] = a1;
        *(float4*)&aggs[n2 * CST + c4] = a2;
    }
    __syncthreads();  // S3

    // ---- 4. part4: lane = node, wave owns j-set [16w2, 16w2+16).
    //      z per-lane ds_read_b128 (loaded once); weights = wave-uniform
    //      512B-contiguous scalar runs. acc[16], 2048 FMA/thread. ----
    float acc[16];
#pragma unroll
    for (int k = 0; k < 16; ++k) acc[k] = 0.f;
    for (int q = 0; q < 4; ++q) {
        const float* zsrc = (q < 2 ? aggs : h2s) + lane * CST + (q & 1) * 32;
        float4 z0 = *(const float4*)(zsrc + 0);
        float4 z1 = *(const float4*)(zsrc + 4);
        float4 z2 = *(const float4*)(zsrc + 8);
        float4 z3 = *(const float4*)(zsrc + 12);
        float4 z4 = *(const float4*)(zsrc + 16);
        float4 z5 = *(const float4*)(zsrc + 20);
        float4 z6 = *(const float4*)(zsrc + 24);
        float4 z7 = *(const float4*)(zsrc + 28);
        const float* wq = upkQ + (q * 128 + w2 * 16) * 32;  // uniform base
#pragma unroll
        for (int ji = 0; ji < 16; ++ji) {
            const float* wr = wq + ji * 32;  // contiguous -> s_load run
            float a = acc[ji];
            a += z0.x * wr[0] + z0.y * wr[1] + z0.z * wr[2] + z0.w * wr[3];
            a += z1.x * wr[4] + z1.y * wr[5] + z1.z * wr[6] + z1.w * wr[7];
            a += z2.x * wr[8] + z2.y * wr[9] + z2.z * wr[10] + z2.w * wr[11];
            a += z3.x * wr[12] + z3.y * wr[13] + z3.z * wr[14] + z3.w * wr[15];
            a += z4.x * wr[16] + z4.y * wr[17] + z4.z * wr[18] + z4.w * wr[19];
            a += z5.x * wr[20] + z5.y * wr[21] + z5.z * wr[22] + z5.w * wr[23];
            a += z6.x * wr[24] + z6.y * wr[25] + z6.z * wr[26] + z6.w * wr[27];
            a += z7.x * wr[28] + z7.y * wr[29] + z7.z * wr[30] + z7.w * wr[31];
            acc[ji] = a;
        }
    }
    __syncthreads();  // S4: all aggs/h2s reads done -> tile may overlay

    // ---- 5. reduction via transpose tile (no bpermute storm) ----
#pragma unroll
    for (int k = 0; k < 4; ++k) {
        float4 o;
        o.x = acc[4 * k + 0] + rel_b[w2 * 16 + 4 * k + 0];
        o.y = acc[4 * k + 1] + rel_b[w2 * 16 + 4 * k + 1];
        o.z = acc[4 * k + 2] + rel_b[w2 * 16 + 4 * k + 2];
        o.w = acc[4 * k + 3] + rel_b[w2 * 16 + 4 * k + 3];
        *(float4*)&tile[lane * TST + w2 * 16 + 4 * k] = o;  // tile[node][j]
    }
    __syncthreads();  // S5

    {
        int j = tid & 127, qn = tid >> 7;  // node quarter
        float s = 0.f, qd = 0.f;
#pragma unroll 4
        for (int r = 0; r < 16; ++r) {
            float v = tile[(qn * 16 + r) * TST + j];
            s += v;
            qd += v * v;
        }
        Pred[qn * 128 + j] = s;
        Pred[512 + qn * 128 + j] = qd;
    }
    __syncthreads();  // S6

    if (tid < DHID) {
        float S = Pred[tid] + Pred[128 + tid] + Pred[256 + tid] + Pred[384 + tid];
        float Q = Pred[512 + tid] + Pred[640 + tid] + Pred[768 + tid] + Pred[896 + tid];
        SQl[tid] = S;
        QQl[tid] = Q;
        Sg[(size_t)g * DHID + tid] = S;
        Qg[(size_t)g * DHID + tid] = Q;
    }

    if (!coop) return;  // host fallback runs D/E

    gbar(&bar[0], &bar[1], (unsigned)nb);  // Sg/Qg visible device-wide

    // ---- D: blocks 0..127 compute BN scale/shift for channel j=bid ----
    if (blockIdx.x < DHID) {
        int j = blockIdx.x;
        float s = 0.f, qv = 0.f;
        for (int gi = tid; gi < G; gi += 512) {
            s += Sg[(size_t)gi * DHID + j];
            qv += Qg[(size_t)gi * DHID + j];
        }
#pragma unroll
        for (int off = 32; off; off >>= 1) {
            s += __shfl_xor(s, off);
            qv += __shfl_xor(qv, off);
        }
        if ((tid & 63) == 0) { red[w2] = s; red[8 + w2] = qv; }
        __syncthreads();
        if (tid == 0) {
            s = 0.f; qv = 0.f;
#pragma unroll
            for (int k = 0; k < 8; ++k) { s += red[k]; qv += red[8 + k]; }
            float inv_n = 1.f / (float)N;
            float mean = s * inv_n;
            float var = qv * inv_n - mean * mean;
            float a = rsqrtf(var + 1e-5f) * gamma[j];
            float b = beta[j] - mean * a;
            abG[j] = a;
            abG[DHID + j] = b;
        }
    }

    gbar(&bar[2], &bar[3], (unsigned)nb);  // abG visible device-wide

    // ---- E: per-block head from LDS-stashed S/Q ----
    if (tid < DHID) {
        int j = tid;
        float a = abG[j], b = abG[DHID + j];
        float S = SQl[j], Q = QQl[j];
        float pooled = (a * a * Q + 2.f * a * b * S) * (1.f / 64.f) + b * b;
        float pl = logf(fmaxf(pooled, 1e-6f));
        Pred[j] = pl * fc2_w[j];
        Pred[128 + j] = pl * fc2_w[DHID + j];
        Pred[256 + j] = pl * fc2_w[2 * DHID + j];
    }
    __syncthreads();
    if (tid < 3) {
        float v = fc2_b[tid];
        for (int c = 0; c < DHID; ++c) v += Pred[tid * 128 + c];
        y[(size_t)g * 3 + tid] = 1.f / (1.f + expf(-v));
    }
}

// ---------------------------------------------------------------------------
// Fallback D/E (only if grid can't co-reside -> coop=0; not hit at G=512)
// ---------------------------------------------------------------------------
__global__ __launch_bounds__(256) void phaseD2(const float* __restrict__ Sg,
                                               const float* __restrict__ Qg,
                                               const float* __restrict__ gamma,
                                               const float* __restrict__ beta,
                                               float* __restrict__ ab,
                                               int G, int N) {
    int j = blockIdx.x;
    int t = threadIdx.x;
    float s = 0.f, q = 0.f;
    for (int g = t; g < G; g += 256) {
        s += Sg[g * DHID + j];
        q += Qg[g * DHID + j];
    }
#pragma unroll
    for (int off = 32; off; off >>= 1) {
        s += __shfl_xor(s, off);
        q += __shfl_xor(q, off);
    }
    __shared__ float rs[4], rq[4];
    int wv = t >> 6;
    if ((t & 63) == 0) { rs[wv] = s; rq[wv] = q; }
    __syncthreads();
    if (t == 0) {
        s = rs[0] + rs[1] + rs[2] + rs[3];
        q = rq[0] + rq[1] + rq[2] + rq[3];
        float inv_n = 1.f / (float)N;
        float mean = s * inv_n;
        float var = q * inv_n - mean * mean;
        float a = rsqrtf(var + 1e-5f) * gamma[j];
        float b = beta[j] - mean * a;
        ab[j] = a;
        ab[DHID + j] = b;
    }
}

__global__ __launch_bounds__(128) void phaseE(const float* __restrict__ Sg,
                                              const float* __restrict__ Qg,
                                              const float* __restrict__ ab,
                                              const float* __restrict__ fc2_w,
                                              const float* __restrict__ fc2_b,
                                              float* __restrict__ y) {
    int g = blockIdx.x;
    int j = threadIdx.x;
    __shared__ float ps[DHID];
    float a = ab[j], b = ab[DHID + j];
    float S = Sg[g * DHID + j], Q = Qg[g * DHID + j];
    float pooled = (a * a * Q + 2.f * a * b * S) * (1.f / 64.f) + b * b;
    pooled = fmaxf(pooled, 1e-6f);
    ps[j] = logf(pooled);
    __syncthreads();
    if (j < 3) {
        float acc = fc2_b[j];
        for (int c = 0; c < DHID; ++c) acc += ps[c] * fc2_w[j * DHID + c];
        y[g * 3 + j] = 1.f / (1.f + expf(-acc));
    }
}

// ---------------------------------------------------------------------------
extern "C" void kernel_launch(void* const* d_in, const int* in_sizes, int n_in,
                              void* d_out, int out_size, void* d_ws, size_t ws_size,
                              hipStream_t stream) {
    const float* x      = (const float*)d_in[0];
    const int*   ei     = (const int*)d_in[1];
    const float* conv_w = (const float*)d_in[3];
    const float* conv_b = (const float*)d_in[4];
    const float* fc1_w  = (const float*)d_in[5];
    const float* fc1_b  = (const float*)d_in[6];
    const float* rel_w  = (const float*)d_in[7];
    const float* rel_b  = (const float*)d_in[8];
    const float* root_w = (const float*)d_in[9];
    const float* gamma  = (const float*)d_in[10];
    const float* beta   = (const float*)d_in[11];
    const float* fc2_w  = (const float*)d_in[12];
    const float* fc2_b  = (const float*)d_in[13];
    float* y = (float*)d_out;

    int N = in_sizes[2];       // 32768
    int E = in_sizes[1] / 2;   // 1048576
    int G = N / 64;            // 512

    float* Sg     = (float*)d_ws;                  // G*128
    float* Qg     = Sg + (size_t)G * DHID;         // G*128
    float* Wm     = Qg + (size_t)G * DHID;         // 6464
    float* upkQ   = Wm + 6464;                     // 16384
    float* abG    = upkQ + 16384;                  // 256
    unsigned* bar = (unsigned*)(abG + 256);        // 8

    int coop = (G <= 512) ? 1 : 0;

    packU<<<90, 256, 0, stream>>>(conv_w, conv_b, fc1_w, fc1_b, rel_w, root_w,
                                  Wm, upkQ, bar);
    fused<<<G, 512, 0, stream>>>(x, ei, Wm, upkQ, rel_b, gamma, beta,
                                 fc2_w, fc2_b, Sg, Qg, abG, y, bar,
                                 E, G, N, coop);
    if (!coop) {
        phaseD2<<<DHID, 256, 0, stream>>>(Sg, Qg, gamma, beta, abG, G, N);
        phaseE<<<G, DHID, 0, stream>>>(Sg, Qg, abG, fc2_w, fc2_b, y);
    }
}